// Round 1
// baseline (671.398 us; speedup 1.0000x reference)
//
#include <hip/hip_runtime.h>
#include <math.h>

#define NLAT 361
#define NLON 720
#define EPSF 1e-7f

// ---------------------------------------------------------------------------
// Kernel 1: real DFT over longitude, fused transpose + quadrature-weight fold.
// grid = 16*361 blocks, one per (bc, j) row. 192 threads; threads m=0..180
// produce bins m and 360-m simultaneously.
//
//   F[m]      = f0 + (-1)^m f360 + Sum_{n=1..359} e[n] cos(t m n) - i o[n] sin(t m n)
//   F[360-m]  = f0 + (-1)^m f360 + Sum e[n](-1)^n cos - i * ( -(-1)^n ) o[n] sin
// with e[n]=f[n]+f[720-n], o[n]=f[n]-f[720-n]; route odd/even n into separate
// accumulators so one pass serves both m's.
// Output: G[bc][m][j] = (2*pi/720) * w[j] * F[bc][j][m]   (m = 0..359 only;
// the m=360 Nyquist column is dead under the triangular mask downstream).
// ---------------------------------------------------------------------------
__global__ void dft_kernel(const float* __restrict__ pred,
                           const float* __restrict__ targ,
                           const float* __restrict__ wq,
                           float2* __restrict__ GP,
                           float2* __restrict__ GT) {
  const int blk = blockIdx.x;
  const int bc  = blk / NLAT;
  const int j   = blk - bc * NLAT;
  const float* fp = pred + (size_t)(bc * NLAT + j) * NLON;
  const float* ft = targ + (size_t)(bc * NLAT + j) * NLON;

  __shared__ float4 eo[360];   // (e_p, o_p, e_t, o_t), n = 1..359 ([0] unused)
  __shared__ float2 cs[720];   // (cos, sin)(2*pi*t/720)

  const int tid = threadIdx.x;
  for (int t = tid; t < 360; t += blockDim.x) {
    float s, c;
    sincosf((float)(2.0 * M_PI / 720.0) * (float)t, &s, &c);
    cs[t]       = make_float2(c, s);
    cs[t + 360] = make_float2(-c, -s);
  }
  for (int n = tid; n < 360; n += blockDim.x) {
    if (n >= 1) {
      float a = fp[n], b = fp[NLON - n];
      float c = ft[n], d = ft[NLON - n];
      eo[n] = make_float4(a + b, a - b, c + d, c - d);
    }
  }
  __syncthreads();

  const int m = tid;
  if (m > 180) return;

  const float fp0 = fp[0], fp360 = fp[360];
  const float ft0 = ft[0], ft360 = ft[360];

  float CeP = 0.f, CoP = 0.f, SeP = 0.f, SoP = 0.f;
  float CeT = 0.f, CoT = 0.f, SeT = 0.f, SoT = 0.f;

  const int step = 2 * m;          // <= 360, single conditional subtract ok
  int i1 = m;                      // (2k-1)*m mod 720, k starting at 1
  int i2 = step;                   // (2k)*m   mod 720

  for (int k = 1; k <= 179; ++k) {
    float4 v1 = eo[2 * k - 1];
    float2 t1 = cs[i1];
    CoP += v1.x * t1.x; SoP += v1.y * t1.y;
    CoT += v1.z * t1.x; SoT += v1.w * t1.y;

    float4 v2 = eo[2 * k];
    float2 t2 = cs[i2];
    CeP += v2.x * t2.x; SeP += v2.y * t2.y;
    CeT += v2.z * t2.x; SeT += v2.w * t2.y;

    i1 += step; if (i1 >= 720) i1 -= 720;
    i2 += step; if (i2 >= 720) i2 -= 720;
  }
  { // tail: n = 359 (odd); i1 == 359*m mod 720 here
    float4 v = eo[359];
    float2 t = cs[i1];
    CoP += v.x * t.x; SoP += v.y * t.y;
    CoT += v.z * t.x; SoT += v.w * t.y;
  }

  const float sgn   = (m & 1) ? -1.f : 1.f;
  const float baseP = fp0 + sgn * fp360;
  const float baseT = ft0 + sgn * ft360;
  const float scale = (float)(2.0 * M_PI / 720.0) * wq[j];

  // bin m
  {
    float reP = baseP + CeP + CoP, imP = -(SeP + SoP);
    float reT = baseT + CeT + CoT, imT = -(SeT + SoT);
    GP[((size_t)bc * 360 + m) * NLAT + j] = make_float2(reP * scale, imP * scale);
    GT[((size_t)bc * 360 + m) * NLAT + j] = make_float2(reT * scale, imT * scale);
  }
  // bin 360-m  (m = 1..179; m=180 is self-paired, m=0 pairs to dead bin 360)
  if (m >= 1 && m <= 179) {
    int m2 = 360 - m;
    float reP = baseP + CeP - CoP, imP = SeP - SoP;
    float reT = baseT + CeT - CoT, imT = SeT - SoT;
    GP[((size_t)bc * 360 + m2) * NLAT + j] = make_float2(reP * scale, imP * scale);
    GT[((size_t)bc * 360 + m2) * NLAT + j] = make_float2(reT * scale, imT * scale);
  }
}

// ---------------------------------------------------------------------------
// Kernel 2: Legendre contraction fused with triangular PSD / cross-spectrum.
// C[bc,l,m] = Sum_j leg[l,m,j] * G[bc,m,j]   (complex, for P and T)
// Accumulate over m (eps_m = 1 for m=0 else 2):
//   S[bc][l] = { Sum eps|Cp|^2, Sum eps|Ct|^2, Sum eps Re(Cp conj(Ct)),
//               Sum eps Im(conj(Cp) Ct) }      via atomicAdd.
// block: 256 thr = 16 bc x 16 j-lanes; tile = 8 l-rows x 8 m per block.
// leg rows with m>l are all-zero in the table -> contribute nothing (mask free).
// ---------------------------------------------------------------------------
#define TL 8
#define MC 8
__global__ void leg_kernel(const float* __restrict__ leg,
                           const float2* __restrict__ GP,
                           const float2* __restrict__ GT,
                           float* __restrict__ S) {
  const int l0 = blockIdx.x * TL;   // gridDim.x = 45  (l = 0..359)
  const int m0 = blockIdx.y * MC;   // gridDim.y = 45  (m = 0..359)
  if (m0 > l0 + TL - 1) return;     // whole tile masked out

  __shared__ float slg[TL][NLAT];

  const int tid  = threadIdx.x;
  const int bcid = tid >> 4;
  const int jl   = tid & 15;

  float rpp[TL], rtp[TL], rsr[TL], rsi[TL];
#pragma unroll
  for (int lp = 0; lp < TL; ++lp) { rpp[lp] = rtp[lp] = rsr[lp] = rsi[lp] = 0.f; }

  const int mEnd = (m0 + MC < 360) ? m0 + MC : 360;
  for (int m = m0; m < mEnd; ++m) {
    // stage 8 leg rows: leg[l0+lp][m][0..360]
    for (int idx = tid; idx < TL * NLAT; idx += 256) {
      int lp = idx / NLAT, jj = idx - lp * NLAT;
      slg[lp][jj] = leg[((size_t)(l0 + lp) * NLAT + m) * NLAT + jj];
    }
    __syncthreads();

    float cpr[TL], cpi[TL], ctr[TL], cti[TL];
#pragma unroll
    for (int lp = 0; lp < TL; ++lp) { cpr[lp] = cpi[lp] = ctr[lp] = cti[lp] = 0.f; }

    const float2* gp = GP + ((size_t)bcid * 360 + m) * NLAT;
    const float2* gt = GT + ((size_t)bcid * 360 + m) * NLAT;
    for (int j = jl; j < NLAT; j += 16) {
      float2 vp = gp[j];
      float2 vt = gt[j];
#pragma unroll
      for (int lp = 0; lp < TL; ++lp) {
        float lg = slg[lp][j];
        cpr[lp] += lg * vp.x; cpi[lp] += lg * vp.y;
        ctr[lp] += lg * vt.x; cti[lp] += lg * vt.y;
      }
    }
    // butterfly-reduce across the 16 j-lanes
#pragma unroll
    for (int lp = 0; lp < TL; ++lp) {
#pragma unroll
      for (int off = 8; off > 0; off >>= 1) {
        cpr[lp] += __shfl_xor(cpr[lp], off, 16);
        cpi[lp] += __shfl_xor(cpi[lp], off, 16);
        ctr[lp] += __shfl_xor(ctr[lp], off, 16);
        cti[lp] += __shfl_xor(cti[lp], off, 16);
      }
    }
    if (jl == 0) {
      const float ef = (m == 0) ? 1.f : 2.f;
#pragma unroll
      for (int lp = 0; lp < TL; ++lp) {
        float a2p = cpr[lp] * cpr[lp] + cpi[lp] * cpi[lp];
        float a2t = ctr[lp] * ctr[lp] + cti[lp] * cti[lp];
        float cr  = cpr[lp] * ctr[lp] + cpi[lp] * cti[lp];
        float ci  = cpr[lp] * cti[lp] - cpi[lp] * ctr[lp];
        rpp[lp] += ef * a2p; rtp[lp] += ef * a2t;
        rsr[lp] += ef * cr;  rsi[lp] += ef * ci;
      }
    }
    __syncthreads();
  }

  if (jl == 0) {
#pragma unroll
    for (int lp = 0; lp < TL; ++lp) {
      float* sp = S + ((size_t)bcid * 360 + (l0 + lp)) * 4;
      atomicAdd(sp + 0, rpp[lp]);
      atomicAdd(sp + 1, rtp[lp]);
      atomicAdd(sp + 2, rsr[lp]);
      atomicAdd(sp + 3, rsi[lp]);
    }
  }
}

// ---------------------------------------------------------------------------
// Kernel 3: final loss epilogue + reduction. One block.
// ---------------------------------------------------------------------------
__global__ void loss_kernel(const float* __restrict__ S,
                            const float* __restrict__ wts,
                            float* __restrict__ out) {
  const int tid = threadIdx.x;
  float acc = 0.f;
  for (int i = tid; i < 16 * 360; i += 256) {
    int bc = i / 360;
    const float* sp = S + (size_t)i * 4;
    float pp = sp[0] + EPSF;
    float tp = sp[1] + EPSF;
    float sr = sp[2], si = sp[3];
    float mag   = sqrtf(sr * sr + si * si);
    float denom = sqrtf(pp * tp + EPSF);
    float coh   = mag / (denom + EPSF);
    coh = fminf(fmaxf(coh, 0.f), 1.f);
    float sqp = sqrtf(pp), sqt = sqrtf(tp);
    float amp = (sqp - sqt) * (sqp - sqt);
    float dec = 2.f * fmaxf(pp, tp) * (1.f - coh);
    acc += (amp + dec) * wts[bc & 7];
  }
  __shared__ float red[4];
#pragma unroll
  for (int off = 32; off > 0; off >>= 1) acc += __shfl_xor(acc, off, 64);
  if ((tid & 63) == 0) red[tid >> 6] = acc;
  __syncthreads();
  if (tid == 0) {
    float loss = (red[0] + red[1] + red[2] + red[3]) / (360.f * 16.f);
    out[0] = isnan(loss) ? 1e6f : loss;
  }
}

// ---------------------------------------------------------------------------
extern "C" void kernel_launch(void* const* d_in, const int* in_sizes, int n_in,
                              void* d_out, int out_size, void* d_ws, size_t ws_size,
                              hipStream_t stream) {
  const float* pred = (const float*)d_in[0];   // [2,8,361,720]
  const float* targ = (const float*)d_in[1];   // [2,8,361,720]
  const float* wts  = (const float*)d_in[2];   // [8]
  const float* leg  = (const float*)d_in[3];   // [361,361,361]
  const float* wq   = (const float*)d_in[4];   // [361]
  float* out = (float*)d_out;

  const size_t gElems = (size_t)16 * 360 * NLAT;       // float2 count
  float2* GP = (float2*)d_ws;
  float2* GT = GP + gElems;
  float*  S  = (float*)(GT + gElems);                  // [16][360][4]

  hipMemsetAsync(S, 0, (size_t)16 * 360 * 4 * sizeof(float), stream);

  dft_kernel<<<16 * NLAT, 192, 0, stream>>>(pred, targ, wq, GP, GT);

  dim3 g2(45, 45);
  leg_kernel<<<g2, 256, 0, stream>>>(leg, GP, GT, S);

  loss_kernel<<<1, 256, 0, stream>>>(S, wts, out);
}

// Round 2
// 527.164 us; speedup vs baseline: 1.2736x; 1.2736x over previous
//
#include <hip/hip_runtime.h>
#include <math.h>

#define NLAT 361
#define NLON 720
#define EPSF 1e-7f
#define TWOPI_N 6.283185307179586e+0  // 2*pi; step = TWOPI_N/720

// ---------------------------------------------------------------------------
// Kernel 1: real DFT over longitude, two latitude rows per block (shared
// rotators), fused quadrature weight, output in leg-friendly layout:
//   GG[m][j][bc] = float4( Fp.re, Fp.im, Ft.re, Ft.im ) * (2pi/720) * w[j]
// m = 0..359 (Nyquist bin 360 is dead under the triangular mask).
// Thread m (0..180) produces bins m and 360-m via n-parity routing; per-lane
// incremental complex rotators replace the LDS twiddle table (no bank
// conflicts, no index ALU).
// ---------------------------------------------------------------------------
__global__ void dft_kernel(const float* __restrict__ pred,
                           const float* __restrict__ targ,
                           const float* __restrict__ wq,
                           float4* __restrict__ GG) {
  const int blk = blockIdx.x;          // 16 * 181 blocks
  const int bc  = blk / 181;
  const int p   = blk - bc * 181;
  const int j0  = 2 * p;
  const int j1  = (j0 + 1 <= 360) ? j0 + 1 : j0;   // row 360 pairs with itself

  const float* fp0 = pred + ((size_t)bc * NLAT + j0) * NLON;
  const float* ft0 = targ + ((size_t)bc * NLAT + j0) * NLON;
  const float* fp1 = pred + ((size_t)bc * NLAT + j1) * NLON;
  const float* ft1 = targ + ((size_t)bc * NLAT + j1) * NLON;

  __shared__ float4 eo[2][360];        // (e_p, o_p, e_t, o_t), n=1..359
  const int tid = threadIdx.x;
  for (int idx = tid; idx < 720; idx += 192) {
    int r = idx / 360, n = idx - 360 * r;
    if (n >= 1) {
      const float* a = r ? fp1 : fp0;
      const float* b = r ? ft1 : ft0;
      float a1 = a[n], a2 = a[NLON - n], b1 = b[n], b2 = b[NLON - n];
      eo[r][n] = make_float4(a1 + a2, a1 - a2, b1 + b2, b1 - b2);
    }
  }
  __syncthreads();

  const int m = tid;
  if (m > 180) return;

  // rotators: chain1 at angle (2k-1)*m*t0, chain2 at (2k)*m*t0; step 2m*t0
  float c1, s1, c2, s2, cs, ss;
  {
    float a1 = (float)(TWOPI_N / 720.0 * (double)m);
    float a2 = (float)(TWOPI_N / 720.0 * (double)(2 * m));
    sincosf(a1, &s1, &c1);
    sincosf(a2, &ss, &cs);
    c2 = cs; s2 = ss;
  }

  float CeP0 = 0.f, CoP0 = 0.f, SeP0 = 0.f, SoP0 = 0.f;
  float CeT0 = 0.f, CoT0 = 0.f, SeT0 = 0.f, SoT0 = 0.f;
  float CeP1 = 0.f, CoP1 = 0.f, SeP1 = 0.f, SoP1 = 0.f;
  float CeT1 = 0.f, CoT1 = 0.f, SeT1 = 0.f, SoT1 = 0.f;

#pragma unroll 2
  for (int k = 1; k <= 179; ++k) {
    float4 u0 = eo[0][2 * k - 1], v0 = eo[0][2 * k];
    float4 u1 = eo[1][2 * k - 1], v1 = eo[1][2 * k];
    CoP0 += u0.x * c1; SoP0 += u0.y * s1; CoT0 += u0.z * c1; SoT0 += u0.w * s1;
    CeP0 += v0.x * c2; SeP0 += v0.y * s2; CeT0 += v0.z * c2; SeT0 += v0.w * s2;
    CoP1 += u1.x * c1; SoP1 += u1.y * s1; CoT1 += u1.z * c1; SoT1 += u1.w * s1;
    CeP1 += v1.x * c2; SeP1 += v1.y * s2; CeT1 += v1.z * c2; SeT1 += v1.w * s2;
    float nc1 = c1 * cs - s1 * ss, ns1 = s1 * cs + c1 * ss;
    c1 = nc1; s1 = ns1;
    float nc2 = c2 * cs - s2 * ss, ns2 = s2 * cs + c2 * ss;
    c2 = nc2; s2 = ns2;
  }
  { // tail n = 359 (odd); c1,s1 now at angle 359*m*t0
    float4 u0 = eo[0][359], u1 = eo[1][359];
    CoP0 += u0.x * c1; SoP0 += u0.y * s1; CoT0 += u0.z * c1; SoT0 += u0.w * s1;
    CoP1 += u1.x * c1; SoP1 += u1.y * s1; CoT1 += u1.z * c1; SoT1 += u1.w * s1;
  }

  const float sgn = (m & 1) ? -1.f : 1.f;
  const float t0w = (float)(TWOPI_N / 720.0);
  // row 0
  {
    float baseP = fp0[0] + sgn * fp0[360];
    float baseT = ft0[0] + sgn * ft0[360];
    float sc = t0w * wq[j0];
    float reP = baseP + CeP0 + CoP0, imP = -(SeP0 + SoP0);
    float reT = baseT + CeT0 + CoT0, imT = -(SeT0 + SoT0);
    GG[((size_t)m * NLAT + j0) * 16 + bc] =
        make_float4(reP * sc, imP * sc, reT * sc, imT * sc);
    if (m >= 1 && m <= 179) {
      int m2 = 360 - m;
      float reP2 = baseP + CeP0 - CoP0, imP2 = SeP0 - SoP0;
      float reT2 = baseT + CeT0 - CoT0, imT2 = SeT0 - SoT0;
      GG[((size_t)m2 * NLAT + j0) * 16 + bc] =
          make_float4(reP2 * sc, imP2 * sc, reT2 * sc, imT2 * sc);
    }
  }
  // row 1 (duplicate write when j1==j0 is benign: same thread, same value)
  {
    float baseP = fp1[0] + sgn * fp1[360];
    float baseT = ft1[0] + sgn * ft1[360];
    float sc = t0w * wq[j1];
    float reP = baseP + CeP1 + CoP1, imP = -(SeP1 + SoP1);
    float reT = baseT + CeT1 + CoT1, imT = -(SeT1 + SoT1);
    GG[((size_t)m * NLAT + j1) * 16 + bc] =
        make_float4(reP * sc, imP * sc, reT * sc, imT * sc);
    if (m >= 1 && m <= 179) {
      int m2 = 360 - m;
      float reP2 = baseP + CeP1 - CoP1, imP2 = SeP1 - SoP1;
      float reT2 = baseT + CeT1 - CoT1, imT2 = SeT1 - SoT1;
      GG[((size_t)m2 * NLAT + j1) * 16 + bc] =
          make_float4(reP2 * sc, imP2 * sc, reT2 * sc, imT2 * sc);
    }
  }
}

// ---------------------------------------------------------------------------
// Kernel 2: Legendre contraction + triangular PSD/cross-spectrum, using the
// parity symmetry Pbar_lm(-x) = (-1)^(l+m) Pbar_lm(x): only j=0..180 of the
// leg table is read (halves both fetch and FLOPs). Even/odd-combined G is
// formed in registers from two float4 loads (j and 360-j).
// Block: 256 thr = 16 bc x 4 j-lanes x 4 l-groups; 16 l-rows x 4 m per block.
// Grid: flattened triangular list, 2*23*24 = 1104 blocks.
// leg rows with m>l are zero in the table -> masked for free.
// ---------------------------------------------------------------------------
__global__ void leg_kernel(const float* __restrict__ leg,
                           const float4* __restrict__ GG,
                           float* __restrict__ S) {
  int bid = blockIdx.x;
  int lt = 0, acc = 0;
  while (bid >= acc + 4 * (lt + 1)) { acc += 4 * (lt + 1); ++lt; }
  const int l0 = lt * 16;
  const int m0 = (bid - acc) * 4;

  __shared__ float sLg[181][20];   // transposed tile, stride 20 (16B-aligned,
                                   // 2-way banks only)
  const int tid = threadIdx.x;
  const int bc  = tid >> 4;        // 0..15  (consecutive bc lanes -> full 64B lines)
  const int jl  = (tid >> 2) & 3;  // 0..3   (xor 4/8 shuffle reduction)
  const int lpg = tid & 3;         // 0..3   (l-group: rows lpg*4 .. lpg*4+3)

  float racc[4][4];
#pragma unroll
  for (int r = 0; r < 4; ++r)
#pragma unroll
    for (int c = 0; c < 4; ++c) racc[r][c] = 0.f;

  for (int mi = 0; mi < 4; ++mi) {
    const int m = m0 + mi;
    if (m > 359) break;
    if (mi) __syncthreads();
    // stage leg[l0..l0+15][m][0..180] transposed (coalesced global read)
    for (int idx = tid; idx < 16 * 181; idx += 256) {
      int lp = idx / 181, j = idx - lp * 181;
      int l = l0 + lp;
      sLg[j][lp] = (l <= 360) ? leg[((size_t)l * NLAT + m) * NLAT + j] : 0.f;
    }
    __syncthreads();

    // parity of row lpg*4+0: (l0+m)&1. u0 = A + sgn*B serves even sub-rows,
    // u1 = A - sgn*B odd sub-rows. cf halves the self-paired center j=180.
    const float sgn  = ((l0 + m) & 1) ? -1.f : 1.f;
    const float msgn = -sgn;
    float ca[4][4];
#pragma unroll
    for (int r = 0; r < 4; ++r)
#pragma unroll
      for (int c = 0; c < 4; ++c) ca[r][c] = 0.f;

    const float4* gm = GG + (size_t)m * (NLAT * 16);
#pragma unroll 2
    for (int j = jl; j <= 180; j += 4) {
      float4 A = gm[j * 16 + bc];
      float4 B = gm[(360 - j) * 16 + bc];
      float cf = (j == 180) ? 0.5f : 1.0f;
      float u0x = fmaf(sgn,  B.x, A.x) * cf, u0y = fmaf(sgn,  B.y, A.y) * cf;
      float u0z = fmaf(sgn,  B.z, A.z) * cf, u0w = fmaf(sgn,  B.w, A.w) * cf;
      float u1x = fmaf(msgn, B.x, A.x) * cf, u1y = fmaf(msgn, B.y, A.y) * cf;
      float u1z = fmaf(msgn, B.z, A.z) * cf, u1w = fmaf(msgn, B.w, A.w) * cf;
      float4 lg = *(const float4*)&sLg[j][lpg * 4];
      ca[0][0] += lg.x * u0x; ca[0][1] += lg.x * u0y;
      ca[0][2] += lg.x * u0z; ca[0][3] += lg.x * u0w;
      ca[1][0] += lg.y * u1x; ca[1][1] += lg.y * u1y;
      ca[1][2] += lg.y * u1z; ca[1][3] += lg.y * u1w;
      ca[2][0] += lg.z * u0x; ca[2][1] += lg.z * u0y;
      ca[2][2] += lg.z * u0z; ca[2][3] += lg.z * u0w;
      ca[3][0] += lg.w * u1x; ca[3][1] += lg.w * u1y;
      ca[3][2] += lg.w * u1z; ca[3][3] += lg.w * u1w;
    }
    // reduce across the 4 j-lanes (bits 2..3 of lane id)
#pragma unroll
    for (int r = 0; r < 4; ++r)
#pragma unroll
      for (int c = 0; c < 4; ++c) {
        ca[r][c] += __shfl_xor(ca[r][c], 4);
        ca[r][c] += __shfl_xor(ca[r][c], 8);
      }
    const float ef = (m == 0) ? 1.f : 2.f;
#pragma unroll
    for (int r = 0; r < 4; ++r) {
      float pr = ca[r][0], pi = ca[r][1], tr = ca[r][2], ti = ca[r][3];
      racc[r][0] += ef * (pr * pr + pi * pi);
      racc[r][1] += ef * (tr * tr + ti * ti);
      racc[r][2] += ef * (pr * tr + pi * ti);
      racc[r][3] += ef * (pr * ti - pi * tr);
    }
  }

  if (jl == 0) {
#pragma unroll
    for (int r = 0; r < 4; ++r) {
      int l = l0 + lpg * 4 + r;
      if (l < 360) {
        float* sp = S + ((size_t)bc * 360 + l) * 4;
        atomicAdd(sp + 0, racc[r][0]);
        atomicAdd(sp + 1, racc[r][1]);
        atomicAdd(sp + 2, racc[r][2]);
        atomicAdd(sp + 3, racc[r][3]);
      }
    }
  }
}

// ---------------------------------------------------------------------------
// Kernel 3: final loss epilogue + reduction. One block.
// ---------------------------------------------------------------------------
__global__ void loss_kernel(const float* __restrict__ S,
                            const float* __restrict__ wts,
                            float* __restrict__ out) {
  const int tid = threadIdx.x;
  float acc = 0.f;
  for (int i = tid; i < 16 * 360; i += 256) {
    int bc = i / 360;
    const float* sp = S + (size_t)i * 4;
    float pp = sp[0] + EPSF;
    float tp = sp[1] + EPSF;
    float sr = sp[2], si = sp[3];
    float mag   = sqrtf(sr * sr + si * si);
    float denom = sqrtf(pp * tp + EPSF);
    float coh   = mag / (denom + EPSF);
    coh = fminf(fmaxf(coh, 0.f), 1.f);
    float sqp = sqrtf(pp), sqt = sqrtf(tp);
    float amp = (sqp - sqt) * (sqp - sqt);
    float dec = 2.f * fmaxf(pp, tp) * (1.f - coh);
    acc += (amp + dec) * wts[bc & 7];
  }
  __shared__ float red[4];
#pragma unroll
  for (int off = 32; off > 0; off >>= 1) acc += __shfl_xor(acc, off, 64);
  if ((tid & 63) == 0) red[tid >> 6] = acc;
  __syncthreads();
  if (tid == 0) {
    float loss = (red[0] + red[1] + red[2] + red[3]) / (360.f * 16.f);
    out[0] = isnan(loss) ? 1e6f : loss;
  }
}

// ---------------------------------------------------------------------------
extern "C" void kernel_launch(void* const* d_in, const int* in_sizes, int n_in,
                              void* d_out, int out_size, void* d_ws, size_t ws_size,
                              hipStream_t stream) {
  const float* pred = (const float*)d_in[0];   // [2,8,361,720]
  const float* targ = (const float*)d_in[1];   // [2,8,361,720]
  const float* wts  = (const float*)d_in[2];   // [8]
  const float* leg  = (const float*)d_in[3];   // [361,361,361]
  const float* wq   = (const float*)d_in[4];   // [361]
  float* out = (float*)d_out;

  float4* GG = (float4*)d_ws;                            // [360][361][16] float4
  float*  S  = (float*)(GG + (size_t)360 * NLAT * 16);   // [16][360][4]

  hipMemsetAsync(S, 0, (size_t)16 * 360 * 4 * sizeof(float), stream);

  dft_kernel<<<16 * 181, 192, 0, stream>>>(pred, targ, wq, GG);

  leg_kernel<<<1104, 256, 0, stream>>>(leg, GG, S);

  loss_kernel<<<1, 256, 0, stream>>>(S, wts, out);
}